// Round 3
// baseline (1004.743 us; speedup 1.0000x reference)
//
#include <hip/hip_runtime.h>
#include <math.h>

// Sinkhorn-divergence margin loss, MI355X.
// Scaled domain: F = f/(eps*ln2), M = C/(eps*ln2); softmin via exp2/log2.
// Ragged prefix mask (len_b = length_anchor[b]) exploited with wave-uniform skips.
#define NL 256
#define ND 300
#define NC 5
#define NR 50

constexpr float SCf  = 577.07801635558534f;     // 1/(eps*ln2), eps=0.0025
constexpr float ELNf = 0.0017328679513998632f;  // eps*ln2
constexpr float BL2f = -5.6438561897747247f;    // log2(1/50)
constexpr float NEGB = -1.0e9f;
constexpr float MNEG = -3.0e38f;

// workspace layout (floats)
#define WS_XN   0        // 65536
#define WS_AL2  65536    // 65536
#define WS_YN   131072   // 256
#define WS_PA   131328   // 256
#define WS_QC   131584   // 16
#define WS_S    131600   // 1280

__device__ __forceinline__ float ex2(float x){ return __builtin_amdgcn_exp2f(x); }
__device__ __forceinline__ float lg2(float x){ return __builtin_amdgcn_logf(x); } // v_log_f32 = log2
__device__ __forceinline__ void pin(float& x){ asm volatile("" : "+v"(x)); }

// ---------------- k_pre: norms (scaled) + log2-weights ----------------
__global__ __launch_bounds__(256) void k_pre(const float* __restrict__ anchor,
                                             const float* __restrict__ weight,
                                             const float* __restrict__ t0,
                                             const int* __restrict__ lena,
                                             float* __restrict__ ws){
  const int blk=blockIdx.x, t=threadIdx.x;
  if(blk<256){
    const int len=lena[blk];
    const int lenS=(len+63)&~63;
    const int r=blk*256+t;
    if(t<lenS){
      const float4* row=(const float4*)(anchor+(size_t)r*ND);
      float s=0.f;
      #pragma unroll
      for(int k=0;k<75;k++){ float4 v=row[k];
        s=fmaf(v.x,v.x,fmaf(v.y,v.y,fmaf(v.z,v.z,fmaf(v.w,v.w,s)))); }
      ws[WS_XN+r]=0.5f*SCf*s;
    }
    const float w=weight[r];
    ws[WS_AL2+r]=(w>0.f)?log2f(w):NEGB;
  } else if(t<NC*NR){
    const float4* row=(const float4*)(t0+(size_t)t*ND);
    float s=0.f;
    #pragma unroll
    for(int k=0;k<75;k++){ float4 v=row[k];
      s=fmaf(v.x,v.x,fmaf(v.y,v.y,fmaf(v.z,v.z,fmaf(v.w,v.w,s)))); }
    ws[WS_YN+t]=0.5f*SCf*s;
  }
}

// ---------------- k_ab: blocks 0..255 -> p per b; 256..260 -> q per c ----
// mapping: i=t&255 (row), h=t>>8 (64-col chunk, wave-uniform) -> ragged skip
__global__ __launch_bounds__(1024,4) void k_ab(const float* __restrict__ anchor,
                                               const float* __restrict__ weight,
                                               const float* __restrict__ t0,
                                               const int* __restrict__ lena,
                                               float* __restrict__ ws){
  __shared__ __align__(16) float4 xt4[1288];  // swizzled x-tile: xt4[5r + 2*(r>>6) + d4]
  __shared__ __align__(16) float xnL[256];
  __shared__ __align__(16) float HpP[4*68];   // H padded: col j -> (j>>6)*68+(j&63)
  __shared__ float PM[4*260];                 // per-(chunk,row) partial max
  __shared__ float PS[4*260];                 // per-(chunk,row) partial sum
  __shared__ float red[16];
  __shared__ __align__(16) float MyL[50*52];
  __shared__ float QL[64];
  __shared__ float padL[10240];               // occupancy limiter -> 1 block/CU (256 CUs busy)
  const int blk=blockIdx.x, t=threadIdx.x;
  if(blk<256){
    const int b=blk;
    const int len=lena[b];
    const int lenS=(len+63)&~63;
    if(len==-1) padL[t]=0.f;  // never true (len in 1..256): keeps padL allocated
    const int i=t&255, h=t>>8;
    const float* xb=anchor+(size_t)b*NL*ND;
    if(t<256) xnL[t]=ws[WS_XN+b*256+t];
    const float al2=ws[WS_AL2+b*256+i];
    if(t<256) HpP[(i>>6)*68+(i&63)]=al2;      // P=0 init (rows>=len stay -1e9)
    for(int e=t;e<1040;e+=1024){ PM[e]=MNEG; PS[e]=0.f; }
    const bool act=(i<len)&&(h*64<len);
    float Mr[64];
    #pragma unroll
    for(int j=0;j<64;j++) Mr[j]=0.f;
    // staging indices (reg-prefetch, rows < lenS only)
    const int r0=t/5, d40=t-r0*5;
    const bool st0=(r0<lenS);
    const int e1=t+1024;
    const int r1=e1/5, d41=e1-r1*5;
    const bool st1=(e1<1280)&&(r1<lenS);
    const float* g0p=xb+(size_t)r0*ND+d40*4;
    const float* g1p=xb+(size_t)r1*ND+d41*4;
    const int u0=5*r0+2*(r0>>6)+d40;
    const int u1=5*r1+2*(r1>>6)+d41;
    float4 pf0,pf1;
    if(st0) pf0=*(const float4*)(g0p);
    if(st1) pf1=*(const float4*)(g1p);
    const float4* xrowp=(const float4*)(xb+(size_t)i*ND);
    const int cb=322*h;  // 5*(64h)+2h
    #pragma unroll 1
    for(int tile=0;tile<15;tile++){
      __syncthreads();
      if(st0) xt4[u0]=pf0;
      if(st1) xt4[u1]=pf1;
      __syncthreads();
      if(tile<14){
        if(st0) pf0=*(const float4*)(g0p+(tile+1)*20);
        if(st1) pf1=*(const float4*)(g1p+(tile+1)*20);
      }
      if(act){
        const float4 xq0=xrowp[tile*5+0];
        const float4 xq1=xrowp[tile*5+1];
        const float4 xq2=xrowp[tile*5+2];
        const float4 xq3=xrowp[tile*5+3];
        const float4 xq4=xrowp[tile*5+4];
        #pragma unroll
        for(int jj=0;jj<64;jj++){
          const float4 y0=xt4[cb+5*jj+0];
          const float4 y1=xt4[cb+5*jj+1];
          const float4 y2=xt4[cb+5*jj+2];
          const float4 y3=xt4[cb+5*jj+3];
          const float4 y4=xt4[cb+5*jj+4];
          float acc=Mr[jj];
          acc=fmaf(xq0.x,y0.x,fmaf(xq0.y,y0.y,fmaf(xq0.z,y0.z,fmaf(xq0.w,y0.w,acc))));
          acc=fmaf(xq1.x,y1.x,fmaf(xq1.y,y1.y,fmaf(xq1.z,y1.z,fmaf(xq1.w,y1.w,acc))));
          acc=fmaf(xq2.x,y2.x,fmaf(xq2.y,y2.y,fmaf(xq2.z,y2.z,fmaf(xq2.w,y2.w,acc))));
          acc=fmaf(xq3.x,y3.x,fmaf(xq3.y,y3.y,fmaf(xq3.z,y3.z,fmaf(xq3.w,y3.w,acc))));
          acc=fmaf(xq4.x,y4.x,fmaf(xq4.y,y4.y,fmaf(xq4.z,y4.z,fmaf(xq4.w,y4.w,acc))));
          Mr[jj]=acc;
        }
      }
    }
    if(act){
      const float xni=xnL[i];
      #pragma unroll
      for(int jj=0;jj<64;jj++) Mr[jj]=xni+xnL[h*64+jj]-SCf*Mr[jj];
    }
    __syncthreads();
    float Pi=0.f;
    const float4* Hp4=(const float4*)HpP;
    #pragma unroll 1
    for(int it=0; it<51; ++it){
      if(act){
        float m0=MNEG,m1=MNEG,m2=MNEG,m3=MNEG;
        #pragma unroll
        for(int q=0;q<16;q++){
          const float4 hv=Hp4[h*17+q];
          m0=fmaxf(m0,hv.x-Mr[q*4+0]); m1=fmaxf(m1,hv.y-Mr[q*4+1]);
          m2=fmaxf(m2,hv.z-Mr[q*4+2]); m3=fmaxf(m3,hv.w-Mr[q*4+3]);
        }
        const float m=fmaxf(fmaxf(m0,m1),fmaxf(m2,m3));
        float s0=0.f,s1=0.f,s2=0.f,s3=0.f;
        #pragma unroll
        for(int q=0;q<16;q++){
          const float4 hv=Hp4[h*17+q];
          s0+=ex2(hv.x-Mr[q*4+0]-m); s1+=ex2(hv.y-Mr[q*4+1]-m);
          s2+=ex2(hv.z-Mr[q*4+2]-m); s3+=ex2(hv.w-Mr[q*4+3]-m);
        }
        PM[h*260+i]=m;
        PS[h*260+i]=(s0+s1)+(s2+s3);
      }
      __syncthreads();
      if(t<256 && i<len){
        const float p0=PM[i],p1=PM[260+i],p2=PM[520+i],p3=PM[780+i];
        const float mm=fmaxf(fmaxf(p0,p1),fmaxf(p2,p3));
        const float ssv=PS[i]*ex2(p0-mm)+PS[260+i]*ex2(p1-mm)
                       +PS[520+i]*ex2(p2-mm)+PS[780+i]*ex2(p3-mm);
        const float sm=-(mm+lg2(ssv));
        Pi=(it==0)?sm:0.5f*(Pi+sm);
        HpP[(i>>6)*68+(i&63)]=al2+Pi;
      }
      __syncthreads();
    }
    float cv=(t<256 && i<len)?(weight[b*256+i]*Pi):0.f;
    #pragma unroll
    for(int off=1;off<64;off<<=1) cv+=__shfl_xor(cv,off);
    if((t&63)==0) red[t>>6]=cv;
    __syncthreads();
    if(t==0){ float ss=0.f;
      #pragma unroll
      for(int k=0;k<16;k++) ss+=red[k];
      ws[WS_PA+b]=ELNf*ss; }
  } else {
    const int c=blk-256;
    const float* yc=t0+(size_t)c*NR*ND;
    #pragma unroll 1
    for(int rr=0;rr<3;rr++){
      const int o=t+1024*rr;
      if(o<2500){
        const int j=o/50, k=o-j*50;
        const float4* a4=(const float4*)(yc+(size_t)j*ND);
        const float4* b4=(const float4*)(yc+(size_t)k*ND);
        float s=0.f;
        #pragma unroll
        for(int d4=0;d4<75;d4++){ const float4 av=a4[d4],bv=b4[d4];
          s=fmaf(av.x,bv.x,fmaf(av.y,bv.y,fmaf(av.z,bv.z,fmaf(av.w,bv.w,s)))); }
        MyL[j*52+k]=ws[WS_YN+c*50+j]+ws[WS_YN+c*50+k]-SCf*s;
      }
    }
    if(t<64) QL[t]=0.f;
    __syncthreads();
    float My[50]; float Qj=0.f;
    if(t<50){
      #pragma unroll
      for(int k=0;k<50;k++) My[k]=MyL[t*52+k];
    }
    #pragma unroll 1
    for(int it=0; it<51; ++it){
      float sm=0.f;
      if(t<50){
        float m=MNEG; float sc[50];
        #pragma unroll
        for(int k=0;k<50;k++){ sc[k]=BL2f+QL[k]-My[k]; m=fmaxf(m,sc[k]); }
        float s=0.f;
        #pragma unroll
        for(int k=0;k<50;k++) s+=ex2(sc[k]-m);
        sm=-(m+lg2(s));
      }
      __syncthreads();
      if(t<50){ Qj=(it==0)?sm:0.5f*(Qj+sm); QL[t]=Qj; }
      __syncthreads();
    }
    float cv=(t<64)?((t<50)?Qj:0.f):0.f;
    if(t<64){
      #pragma unroll
      for(int off=1;off<64;off<<=1) cv+=__shfl_xor(cv,off);
    }
    if(t==0) ws[WS_QC+c]=ELNf*0.02f*cv;
  }
}

// ---------------- k_c: f,g iteration per (b,c); 512 thr ----------------
// f-pass: i=t>>1, h=t&1 (2 thr/row, 25 cols each)
// g-pass: chunk=t>>6 (wave-uniform 32-row chunk), col=t&63 (<50); LDS combine
__global__ __launch_bounds__(512,4) void k_c(const float* __restrict__ anchor,
                                             const float* __restrict__ weight,
                                             const float* __restrict__ t0,
                                             const int* __restrict__ lena,
                                             float* __restrict__ ws){
  __shared__ __align__(16) float4 MTg[50*65]; // M^T: [col j][unit u=row/4], stride 65 units
  __shared__ __align__(16) float yt[1000];    // y-tile [50][20]
  __shared__ float ynL[52];
  __shared__ __align__(16) float AfP[8*36];   // Al2+F padded: row r -> (r>>5)*36+(r&31)
  __shared__ float GL[52];
  __shared__ float PM[8*52];
  __shared__ float PS[8*52];
  __shared__ float red[8];
  const int blk=blockIdx.x, t=threadIdx.x;
  const int c=blk>>8, b=blk&255;
  const int len=lena[b];
  const int i=t>>1, h=t&1;
  const int chunk=t>>6, col=t&63;
  const bool rowAct=(i<len);
  const bool gAct=(chunk*32<len)&&(col<50);
  const float* xb=anchor+(size_t)b*NL*ND;
  const float* yc=t0+(size_t)c*NR*ND;
  if(t<50){ ynL[t]=ws[WS_YN+c*50+t]; GL[t]=0.f; }
  if(t<416){ PM[t]=MNEG; PS[t]=0.f; }
  const float al2=ws[WS_AL2+b*256+i];
  float Mr[25];
  #pragma unroll
  for(int k=0;k<25;k++) Mr[k]=0.f;
  // staging (reg-prefetch)
  const int sr=(t<250)?(t/5):0, sd=(t<250)?(t-(t/5)*5):0;
  const bool stg=(t<250);
  const float* gsp=yc+(size_t)sr*ND+sd*4;
  float4 pf;
  if(stg) pf=*(const float4*)gsp;
  #pragma unroll 1
  for(int tile=0;tile<15;tile++){
    __syncthreads();
    if(stg) *(float4*)&yt[sr*20+sd*4]=pf;
    __syncthreads();
    if(tile<14 && stg) pf=*(const float4*)(gsp+(tile+1)*20);
    if(rowAct){
      const float4* xrow=(const float4*)(xb+(size_t)i*ND+tile*20);
      const float4 xq0=xrow[0],xq1=xrow[1],xq2=xrow[2],xq3=xrow[3],xq4=xrow[4];
      #pragma unroll
      for(int k=0;k<25;k++){
        const int j=2*k+h;
        const float4 y0=*(const float4*)&yt[j*20+0];
        const float4 y1=*(const float4*)&yt[j*20+4];
        const float4 y2=*(const float4*)&yt[j*20+8];
        const float4 y3=*(const float4*)&yt[j*20+12];
        const float4 y4=*(const float4*)&yt[j*20+16];
        float acc=Mr[k];
        acc=fmaf(xq0.x,y0.x,fmaf(xq0.y,y0.y,fmaf(xq0.z,y0.z,fmaf(xq0.w,y0.w,acc))));
        acc=fmaf(xq1.x,y1.x,fmaf(xq1.y,y1.y,fmaf(xq1.z,y1.z,fmaf(xq1.w,y1.w,acc))));
        acc=fmaf(xq2.x,y2.x,fmaf(xq2.y,y2.y,fmaf(xq2.z,y2.z,fmaf(xq2.w,y2.w,acc))));
        acc=fmaf(xq3.x,y3.x,fmaf(xq3.y,y3.y,fmaf(xq3.z,y3.z,fmaf(xq3.w,y3.w,acc))));
        acc=fmaf(xq4.x,y4.x,fmaf(xq4.y,y4.y,fmaf(xq4.z,y4.z,fmaf(xq4.w,y4.w,acc))));
        Mr[k]=acc;
      }
    }
  }
  if(rowAct){
    const float xni=ws[WS_XN+b*256+i];
    #pragma unroll
    for(int k=0;k<25;k++) Mr[k]=xni+ynL[2*k+h]-SCf*Mr[k];
  }
  // transpose into MTg: row i -> unit i>>2, comp i&3 (rows>=len write 0: finite)
  {
    const int QQ=i>>2, cc2=i&3;
    #pragma unroll
    for(int k=0;k<25;k++){
      ((float*)&MTg[(2*k+h)*65+QQ])[cc2]=Mr[k];
    }
  }
  if(h==0) AfP[(i>>5)*36+(i&31)]=al2;   // F=0 init (rows>=len stay -1e9)
  __syncthreads();
  float Fi=0.f, Gj=0.f;
  #pragma unroll 1
  for(int it=0; it<51; ++it){
    float smf=0.f;
    if(rowAct){
      float scf[25];
      float mf=MNEG;
      #pragma unroll
      for(int k=0;k<25;k++){
        scf[k]=BL2f+GL[2*k+h]-Mr[k];
        pin(scf[k]);
        mf=fmaxf(mf,scf[k]);
      }
      mf=fmaxf(mf,__shfl_xor(mf,1));
      float f0=0.f,f1=0.f,f2=0.f,f3=0.f;
      #pragma unroll
      for(int k=0;k<24;k+=4){
        f0+=ex2(scf[k+0]-mf); f1+=ex2(scf[k+1]-mf);
        f2+=ex2(scf[k+2]-mf); f3+=ex2(scf[k+3]-mf);
      }
      f0+=ex2(scf[24]-mf);
      float fs=(f0+f1)+(f2+f3);
      fs+=__shfl_xor(fs,1);
      smf=-(mf+lg2(fs));
    }
    if(gAct){
      float scg[32];
      float g0=MNEG,g1=MNEG,g2=MNEG,g3=MNEG;
      #pragma unroll
      for(int r4=0;r4<8;r4++){
        const float4 av=*(const float4*)&AfP[chunk*36+4*r4];
        const float4 mv=MTg[col*65+chunk*8+r4];
        const float u0=av.x-mv.x, u1=av.y-mv.y, u2=av.z-mv.z, u3=av.w-mv.w;
        scg[4*r4+0]=u0; scg[4*r4+1]=u1; scg[4*r4+2]=u2; scg[4*r4+3]=u3;
        pin(scg[4*r4+0]); pin(scg[4*r4+1]); pin(scg[4*r4+2]); pin(scg[4*r4+3]);
        g0=fmaxf(g0,u0); g1=fmaxf(g1,u1); g2=fmaxf(g2,u2); g3=fmaxf(g3,u3);
      }
      const float gm=fmaxf(fmaxf(g0,g1),fmaxf(g2,g3));
      float s0=0.f,s1=0.f,s2=0.f,s3=0.f;
      #pragma unroll
      for(int r4=0;r4<8;r4++){
        s0+=ex2(scg[4*r4+0]-gm); s1+=ex2(scg[4*r4+1]-gm);
        s2+=ex2(scg[4*r4+2]-gm); s3+=ex2(scg[4*r4+3]-gm);
      }
      PM[chunk*52+col]=gm;
      PS[chunk*52+col]=(s0+s1)+(s2+s3);
    }
    __syncthreads();
    if(rowAct){
      Fi=(it==0)?smf:0.5f*(Fi+smf);
      if(h==0) AfP[(i>>5)*36+(i&31)]=al2+Fi;
    }
    if(t<50){
      float pmv[8];
      float mm=MNEG;
      #pragma unroll
      for(int c2=0;c2<8;c2++){ pmv[c2]=PM[c2*52+t]; mm=fmaxf(mm,pmv[c2]); }
      float ssv=0.f;
      #pragma unroll
      for(int c2=0;c2<8;c2++) ssv+=PS[c2*52+t]*ex2(pmv[c2]-mm);
      const float smg=-(mm+lg2(ssv));
      Gj=(it==0)?smg:0.5f*(Gj+smg);
      GL[t]=Gj;
    }
    __syncthreads();
  }
  // S[b,c] = ELN*(sum_i a_i F_i + 0.02*sum_j G_j)
  float cv=(h==0 && rowAct)?(weight[b*256+i]*Fi):0.f;
  #pragma unroll
  for(int off=1;off<64;off<<=1) cv+=__shfl_xor(cv,off);
  if((t&63)==0) red[t>>6]=cv;
  float gv=(t<50)?Gj:0.f;
  if(t<64){
    #pragma unroll
    for(int off=1;off<64;off<<=1) gv+=__shfl_xor(gv,off);
  }
  __syncthreads();
  if(t==0){
    float sa=0.f;
    #pragma unroll
    for(int k=0;k<8;k++) sa+=red[k];
    ws[WS_S+b*NC+c]=ELNf*(sa+0.02f*gv);
  }
}

// ---------------- k_d: margin loss + mean ----------------
__global__ __launch_bounds__(256) void k_d(const int* __restrict__ grade,
                                           const float* __restrict__ ws,
                                           float* __restrict__ out){
  __shared__ float red[4];
  const int t=threadIdx.x;
  const int g=grade[t];
  const float pa=ws[WS_PA+t];
  const float d0=ws[WS_S+t*NC+0]-pa-ws[WS_QC+0];
  const float d1=ws[WS_S+t*NC+1]-pa-ws[WS_QC+1];
  const float d2=ws[WS_S+t*NC+2]-pa-ws[WS_QC+2];
  const float d3=ws[WS_S+t*NC+3]-pa-ws[WS_QC+3];
  const float d4=ws[WS_S+t*NC+4]-pa-ws[WS_QC+4];
  const float pos=(g==0)?d0:(g==1)?d1:(g==2)?d2:(g==3)?d3:d4;
  float loss=0.f;
  if(g!=0) loss+=fmaxf(0.f,pos-d0+10.f);
  if(g!=1) loss+=fmaxf(0.f,pos-d1+10.f);
  if(g!=2) loss+=fmaxf(0.f,pos-d2+10.f);
  if(g!=3) loss+=fmaxf(0.f,pos-d3+10.f);
  if(g!=4) loss+=fmaxf(0.f,pos-d4+10.f);
  loss*=0.2f;
  #pragma unroll
  for(int off=1;off<64;off<<=1) loss+=__shfl_xor(loss,off);
  if((t&63)==0) red[t>>6]=loss;
  __syncthreads();
  if(t==0) out[0]=(red[0]+red[1]+red[2]+red[3])*(1.f/256.f);
}

extern "C" void kernel_launch(void* const* d_in, const int* in_sizes, int n_in,
                              void* d_out, int out_size, void* d_ws, size_t ws_size,
                              hipStream_t stream){
  (void)in_sizes;(void)n_in;(void)out_size;(void)ws_size;
  const float* anchor=(const float*)d_in[0];
  const float* weight=(const float*)d_in[1];
  const float* t0    =(const float*)d_in[2];
  const int*   lena  =(const int*)d_in[4];
  const int*   grade =(const int*)d_in[5];
  float* ws=(float*)d_ws;
  float* out=(float*)d_out;
  k_pre<<<257,256,0,stream>>>(anchor,weight,t0,lena,ws);
  k_ab <<<261,1024,0,stream>>>(anchor,weight,t0,lena,ws);
  k_c  <<<1280,512,0,stream>>>(anchor,weight,t0,lena,ws);
  k_d  <<<1,256,0,stream>>>(grade,ws,out);
}